// Round 1
// baseline (575.594 us; speedup 1.0000x reference)
//
#include <hip/hip_runtime.h>
#include <math.h>

#define TOKENS 16384
#define HIDDEN 4096
#define NEXP   64
#define TPB    512          // 8 waves
#define TOK_PER_BLK 64
#define KC     128          // k-chunk staged in LDS
#define EPW    8            // experts per wave (8 waves x 8 = 64)

// Kernel A: transpose weight [64,4096] -> Wt [4096,64]  (write-coalesced)
__global__ void transpose_w(const float* __restrict__ W, float* __restrict__ Wt) {
    int idx = blockIdx.x * blockDim.x + threadIdx.x;   // 0..262143
    int k = idx >> 6;        // 0..4095
    int e = idx & 63;        // 0..63
    Wt[idx] = W[(size_t)e * HIDDEN + k];
}

__global__ __launch_bounds__(TPB, 1) void router_main(
    const float* __restrict__ x, const float* __restrict__ Wt,
    float* __restrict__ out)
{
    // 64 rows x 33 float4 (row pad +1 float4 keeps ds_read_b128 conflict-free)
    __shared__ float4 xs[TOK_PER_BLK][KC / 4 + 1];

    const int tid = threadIdx.x;
    const int t   = tid & 63;                                   // lane = token
    const int wv  = __builtin_amdgcn_readfirstlane(tid >> 6);   // wave id 0..7, uniform
    const int tokenBase = blockIdx.x * TOK_PER_BLK;

    float acc[EPW];
    #pragma unroll
    for (int j = 0; j < EPW; ++j) acc[j] = 0.f;

    const float* wbase = Wt + wv * EPW;   // this wave's 8-expert column slice

    for (int k0 = 0; k0 < HIDDEN; k0 += KC) {
        // ---- stage x chunk: 64 tokens x 128 k = 2048 float4, 4 per thread ----
        #pragma unroll
        for (int r = 0; r < 4; ++r) {
            int lin = tid + r * TPB;     // 0..2047
            int tok = lin >> 5;          // 0..63
            int kq  = lin & 31;          // 0..31
            xs[tok][kq] = *reinterpret_cast<const float4*>(
                x + (size_t)(tokenBase + tok) * HIDDEN + k0 + kq * 4);
        }
        __syncthreads();

        const float* wp = wbase + (size_t)k0 * NEXP;
        #pragma unroll 8
        for (int kq = 0; kq < KC / 4; ++kq) {
            float4 x4 = xs[t][kq];
            const float* w0 = wp + kq * 4 * NEXP;
            #pragma unroll
            for (int i = 0; i < 4; ++i) {
                const float* wr = w0 + i * NEXP;     // uniform address -> SMEM hopefully
                float xi = (i == 0) ? x4.x : (i == 1) ? x4.y : (i == 2) ? x4.z : x4.w;
                #pragma unroll
                for (int j = 0; j < EPW; ++j)
                    acc[j] = fmaf(xi, wr[j], acc[j]);
            }
        }
        __syncthreads();
    }

    // ---- epilogue: gather 64 logits per token in LDS, top-2 + softmax ----
    float* logs = reinterpret_cast<float*>(xs);   // 64*65 floats = 16.6 KB, fits
    #pragma unroll
    for (int j = 0; j < EPW; ++j)
        logs[t * (NEXP + 1) + wv * EPW + j] = acc[j];
    __syncthreads();

    if (tid < TOK_PER_BLK) {
        float v1 = -INFINITY, v2 = -INFINITY;
        int   i1 = 0,         i2 = 0;
        #pragma unroll 8
        for (int e = 0; e < NEXP; ++e) {
            float v = logs[tid * (NEXP + 1) + e];
            // strict > : ties keep the lower index first, matching jax.lax.top_k
            if (v > v1)      { v2 = v1; i2 = i1; v1 = v; i1 = e; }
            else if (v > v2) { v2 = v;  i2 = e; }
        }
        float e2 = expf(v2 - v1);           // <= 1, no overflow
        float d  = 1.f / (1.f + e2);
        int tokG = tokenBase + tid;
        out[tokG * 2 + 0] = d;              // softmax weight of top-1
        out[tokG * 2 + 1] = e2 * d;         // softmax weight of top-2
        out[2 * TOKENS + tokG * 2 + 0] = (float)i1;   // indices as f32 values
        out[2 * TOKENS + tokG * 2 + 1] = (float)i2;
    }
}

extern "C" void kernel_launch(void* const* d_in, const int* in_sizes, int n_in,
                              void* d_out, int out_size, void* d_ws, size_t ws_size,
                              hipStream_t stream) {
    const float* x = (const float*)d_in[0];     // [16384, 4096]
    const float* W = (const float*)d_in[1];     // [64, 4096]
    float* out = (float*)d_out;                 // 65536 f32: weights then indices
    float* Wt  = (float*)d_ws;                  // 4096*64 f32 = 1 MB scratch

    transpose_w<<<(NEXP * HIDDEN) / 256, 256, 0, stream>>>(W, Wt);
    router_main<<<TOKENS / TOK_PER_BLK, TPB, 0, stream>>>(x, Wt, out);
}

// Round 2
// 493.169 us; speedup vs baseline: 1.1671x; 1.1671x over previous
//
#include <hip/hip_runtime.h>
#include <math.h>

#define TOKENS 16384
#define HIDDEN 4096
#define NEXP   64
#define TPB    512          // 8 waves
#define TOKB   64           // tokens per block
#define KC     128          // k-chunk staged in LDS
#define EPW    8            // experts per wave

// transpose weight [64,4096] -> Wt [4096,64] (write-coalesced; W L2-resident)
__global__ void transpose_w(const float* __restrict__ W, float* __restrict__ Wt) {
    int idx = blockIdx.x * blockDim.x + threadIdx.x;   // 0..262143
    int k = idx >> 6;
    int e = idx & 63;
    Wt[idx] = W[(size_t)e * HIDDEN + k];
}

// Pass 1: partial logits over a k-slice. grid = (TOKENS/TOKB, nslices).
// partial layout: [slice][expert][token] so pass-2 reads are lane-coalesced.
__global__ __launch_bounds__(TPB, 8) void router_partial(
    const float* __restrict__ x, const float* __restrict__ Wt,
    float* __restrict__ partial, int kslice)
{
    // 64 rows x 33 float4: +1 float4 row pad keeps ds_read_b128 conflict-free
    __shared__ float4 xs[TOKB][KC / 4 + 1];

    const int tid = threadIdx.x;
    const int t   = tid & 63;                                   // lane = token
    const int wv  = __builtin_amdgcn_readfirstlane(tid >> 6);   // wave id, uniform
    const int tokenBase = blockIdx.x * TOKB;
    const int kBase = blockIdx.y * kslice;

    float acc[EPW];
    #pragma unroll
    for (int j = 0; j < EPW; ++j) acc[j] = 0.f;

    const float* wbase = Wt + wv * EPW;   // this wave's 8-expert column slice

    for (int kc = 0; kc < kslice; kc += KC) {
        const int k0 = kBase + kc;
        // stage x chunk: 64 tokens x 128 k = 2048 float4, 4 per thread
        #pragma unroll
        for (int r = 0; r < 4; ++r) {
            int lin = tid + r * TPB;
            int tok = lin >> 5;
            int kq  = lin & 31;
            xs[tok][kq] = *reinterpret_cast<const float4*>(
                x + (size_t)(tokenBase + tok) * HIDDEN + k0 + kq * 4);
        }
        __syncthreads();

        const float* wp = wbase + (size_t)k0 * NEXP;
        #pragma unroll 8
        for (int kq = 0; kq < KC / 4; ++kq) {
            float4 x4 = xs[t][kq];
            const float* w0 = wp + kq * 4 * NEXP;
            #pragma unroll
            for (int i = 0; i < 4; ++i) {
                const float* wr = w0 + i * NEXP;   // wave-uniform -> s_load_dwordx8
                float xi = (i == 0) ? x4.x : (i == 1) ? x4.y : (i == 2) ? x4.z : x4.w;
                #pragma unroll
                for (int j = 0; j < EPW; ++j)
                    acc[j] = fmaf(xi, wr[j], acc[j]);
            }
        }
        __syncthreads();
    }

    // write partials: per (wave, j): 64 consecutive tokens -> coalesced 256B
    float* pbase = partial + ((size_t)blockIdx.y * NEXP + wv * EPW) * TOKENS
                 + tokenBase + t;
    #pragma unroll
    for (int j = 0; j < EPW; ++j)
        pbase[(size_t)j * TOKENS] = acc[j];
}

// Pass 2: sum slices, top-2, softmax. One thread per token; reads coalesced.
__global__ void reduce_topk(const float* __restrict__ partial,
                            float* __restrict__ out, int nslices)
{
    int t = blockIdx.x * blockDim.x + threadIdx.x;
    float v1 = -INFINITY, v2 = -INFINITY;
    int i1 = 0, i2 = 0;
    #pragma unroll 4
    for (int e = 0; e < NEXP; ++e) {
        float v = 0.f;
        for (int s = 0; s < nslices; ++s)              // fixed order: deterministic
            v += partial[((size_t)s * NEXP + e) * TOKENS + t];
        if (v > v1)      { v2 = v1; i2 = i1; v1 = v; i1 = e; }
        else if (v > v2) { v2 = v;  i2 = e; }
    }
    float e2 = expf(v2 - v1);
    float d  = 1.f / (1.f + e2);
    out[t * 2 + 0] = d;
    out[t * 2 + 1] = e2 * d;
    out[2 * TOKENS + t * 2 + 0] = (float)i1;
    out[2 * TOKENS + t * 2 + 1] = (float)i2;
}

extern "C" void kernel_launch(void* const* d_in, const int* in_sizes, int n_in,
                              void* d_out, int out_size, void* d_ws, size_t ws_size,
                              hipStream_t stream) {
    const float* x = (const float*)d_in[0];     // [16384, 4096]
    const float* W = (const float*)d_in[1];     // [64, 4096]
    float* out = (float*)d_out;
    float* Wt  = (float*)d_ws;                                  // 1 MB
    float* partial = Wt + (size_t)NEXP * HIDDEN;                // after Wt

    const size_t wtBytes = (size_t)NEXP * HIDDEN * sizeof(float);
    const size_t sliceBytes = (size_t)NEXP * TOKENS * sizeof(float);  // 4 MB
    int nsl;
    if      (ws_size >= wtBytes + 4 * sliceBytes) nsl = 4;
    else if (ws_size >= wtBytes + 2 * sliceBytes) nsl = 2;
    else                                          nsl = 1;
    const int kslice = HIDDEN / nsl;

    transpose_w<<<(NEXP * HIDDEN) / 256, 256, 0, stream>>>(W, Wt);
    dim3 grid(TOKENS / TOKB, nsl);
    router_partial<<<grid, TPB, 0, stream>>>(x, Wt, partial, kslice);
    reduce_topk<<<TOKENS / 256, 256, 0, stream>>>(partial, out, nsl);
}